// Round 14
// baseline (408.518 us; speedup 1.0000x reference)
//
#include <hip/hip_runtime.h>
#include <hip/hip_bf16.h>
#include <stdint.h>

#define M_POS 0.5f
#define M_NEG 0.1f
#define LAM_NEG 1.0f

typedef __attribute__((ext_vector_type(4))) float floatx4;  // 16x16 MFMA accumulator
typedef __attribute__((ext_vector_type(8))) int   intx8;    // 32B fp8 operand (K=128)

union Frag8 { intx8 v; int4 q[2]; };

// ---------------- Kernel A: row sumsq, inv_norm, fp32 -> fp8(e4m3) quantize, zero accs ----
__global__ __launch_bounds__(256) void prep_kernel(
    const float* __restrict__ cb, unsigned char* __restrict__ cb_q,
    float* __restrict__ sq, float* __restrict__ inv_norm,
    unsigned* __restrict__ zero_base, int zero_len,
    int N, int d)
{
    const int gi = blockIdx.x * 256 + threadIdx.x;
    if (gi < zero_len) zero_base[gi] = 0u;

    const int row = blockIdx.x;
    const float* src = cb + (size_t)row * d;
    unsigned char* dst = cb_q + (size_t)row * d;
    const int t = threadIdx.x;

    float s = 0.f;
    for (int c = t * 4; c < d; c += 1024) {
        float4 v = *(const float4*)(src + c);
        s += v.x * v.x + v.y * v.y + v.z * v.z + v.w * v.w;
        int pk = __builtin_amdgcn_cvt_pk_fp8_f32(v.x, v.y, 0, false);   // bytes 0,1
        pk     = __builtin_amdgcn_cvt_pk_fp8_f32(v.z, v.w, pk, true);   // bytes 2,3
        *(int*)(dst + c) = pk;
    }
    for (int o = 32; o > 0; o >>= 1) s += __shfl_down(s, o, 64);
    __shared__ float wsum[4];
    if ((t & 63) == 0) wsum[t >> 6] = s;
    __syncthreads();
    if (t == 0) {
        float tot = wsum[0] + wsum[1] + wsum[2] + wsum[3];
        sq[row] = tot;
        inv_norm[row] = rsqrtf(tot);
    }
}

// ---------------- Kernel B: 1-WAVE blocks, barrier-free symmetric MX-fp8 Gram + loss ------
// R14: the stall history (R7/R9/R11/R12/R13) indicts barrier-group convergence, so remove
// the barrier: 64-thread workgroups, each wave owns a 64x64 tile (triangular, nb=64-tiles),
// BK=128, MX 16x16x128 unit-scale. K-loop has NO __syncthreads — staging->consume is
// wave-private, ordered by an explicit s_waitcnt vmcnt(0) (0x0f70: exp=7,lgkm=15,vm=0).
// 16 KB LDS/block -> ~10 independent waves/CU, each draining at its own phase.
// Same verified xor swizzle + fragment maps (R8/R13, absmax 0). tid0-only-fence finalize.
__global__ __launch_bounds__(64) void gram_loss_kernel(
    const unsigned char* __restrict__ A,   // N x d fp8
    const float* __restrict__ sq, const float* __restrict__ inv_norm,
    const int* __restrict__ starts, const int* __restrict__ ends,
    const int* __restrict__ max_ip,
    float* __restrict__ pos_acc, float* __restrict__ neg_acc,
    unsigned* __restrict__ counter, float* __restrict__ out,
    int N, int d)
{
    const int M = min(N, max_ip[0] + 1);

    // triangular decode over 64-tiles: blockIdx.x -> (by, bx), by <= bx
    const int t = blockIdx.x;
    int bx = (int)((sqrtf(8.f * (float)t + 1.f) - 1.f) * 0.5f);
    while ((bx + 1) * (bx + 2) / 2 <= t) bx++;
    while (bx * (bx + 1) / 2 > t) bx--;
    const int by = t - bx * (bx + 1) / 2;

    const int rowBase = by * 64;
    const int colBase = bx * 64;
    const bool isDiag = (by == bx);

    __shared__ alignas(16) unsigned char ldsA[64 * 128];
    __shared__ alignas(16) unsigned char ldsB[64 * 128];

    const int lane = threadIdx.x;       // 0..63 (one wave)

    floatx4 acc[4][4];
#pragma unroll
    for (int a = 0; a < 4; ++a)
#pragma unroll
        for (int b = 0; b < 4; ++b) acc[a][b] = (floatx4){0.f, 0.f, 0.f, 0.f};

    // staging: per instr 8 rows x 8 chunks (1 KB); dst lane-linear; src chunk xor lane-const
    const int sRow = lane >> 3;                         // 0..7
    const int sChk = lane & 7;                          // 16B chunk 0..7
    const int srcOffC = ((sChk ^ sRow) * 16);
    const int kTiles = d / 128;                         // 8

    // fragment-read constants: lane holds k = (lane>>4)*32 .. +31 of its row
    const int rl = lane & 15;
    const int g  = lane >> 4;       // 0..3 (k-group)
    const int rx = rl & 7;
    const int c0 = (((2 * g)     ^ rx) * 16);
    const int c1 = (((2 * g + 1) ^ rx) * 16);

    for (int kt = 0; kt < kTiles; ++kt) {
        const int k0 = kt * 128;
#pragma unroll
        for (int h = 0; h < 8; ++h) {
            const int r = h * 8 + sRow;                 // tile row 0..63
            const unsigned char* ga = A + (size_t)(rowBase + r) * d + k0 + srcOffC;
            const unsigned char* gb = A + (size_t)(colBase + r) * d + k0 + srcOffC;
            __builtin_amdgcn_global_load_lds(
                (const __attribute__((address_space(1))) void*)ga,
                (__attribute__((address_space(3))) void*)(ldsA + r * 128 + sChk * 16), 16, 0, 0);
            __builtin_amdgcn_global_load_lds(
                (const __attribute__((address_space(1))) void*)gb,
                (__attribute__((address_space(3))) void*)(ldsB + r * 128 + sChk * 16), 16, 0, 0);
        }
        __builtin_amdgcn_s_waitcnt(0x0f70);   // vmcnt(0): DMA-to-LDS complete (wave-private)

        Frag8 af[4], bf[4];
#pragma unroll
        for (int t4 = 0; t4 < 4; ++t4) {
            const unsigned char* pa = ldsA + (t4 * 16 + rl) * 128;
            af[t4].q[0] = *(const int4*)(pa + c0);
            af[t4].q[1] = *(const int4*)(pa + c1);
            const unsigned char* pb = ldsB + (t4 * 16 + rl) * 128;
            bf[t4].q[0] = *(const int4*)(pb + c0);
            bf[t4].q[1] = *(const int4*)(pb + c1);
        }
#pragma unroll
        for (int rt = 0; rt < 4; ++rt)
#pragma unroll
            for (int ct = 0; ct < 4; ++ct)
                acc[rt][ct] = __builtin_amdgcn_mfma_scale_f32_16x16x128_f8f6f4(
                    af[rt].v, bf[ct].v, acc[rt][ct], 0, 0, 0, 127, 0, 127);
    }

    // ---- epilogue (16x16 C/D: col=lane&15, row=(lane>>4)*4+reg); wave = 64x64 tile ----
    const int q  = g;
    const int jlo = colBase;
    const int ilo = rowBase;

    int   jn[4];
    float jinv[4];
    bool  jvalid[4];
#pragma unroll
    for (int ct = 0; ct < 4; ++ct) {
        const int j = jlo + ct * 16 + rl;
        jn[ct]  = j;
        jinv[ct] = inv_norm[j];
        jvalid[ct] = (j < M);
    }

    // wave-uniform positive-pair possibility check (64 rows, 64 cols)
    bool posLane = false;
    {
        const int ri = ilo + lane;
        if (ri < M) posLane |= (ends[ri] >= jlo) && (starts[ri] <= jlo + 63);
        if (!isDiag) {
            const int cj = jlo + lane;
            if (cj < M) posLane |= (ends[cj] >= ilo) && (starts[cj] <= ilo + 63);
        }
    }
    const bool fullPath = (__ballot(posLane) != 0ULL);

    float posc[4] = {0.f, 0.f, 0.f, 0.f};
    float negc[4] = {0.f, 0.f, 0.f, 0.f};

    if (fullPath) {
        int   jns[4], jne[4];
        float jsq[4];
#pragma unroll
        for (int ct = 0; ct < 4; ++ct) {
            jsq[ct] = sq[jn[ct]];
            jns[ct] = jvalid[ct] ? starts[jn[ct]] : 0;
            jne[ct] = jvalid[ct] ? ends[jn[ct]]   : -1;
        }
#pragma unroll
        for (int rt = 0; rt < 4; ++rt) {
            const int ibase = ilo + rt * 16 + q * 4;
#pragma unroll
            for (int reg = 0; reg < 4; ++reg) {
                const int i = ibase + reg;
                const bool rowValid = (i < M);
                const int ns = rowValid ? starts[i] : 0;
                const int ne = rowValid ? ends[i]   : -1;
                const float iinv = inv_norm[i];
                const float isq  = sq[i];
                float posp = 0.f, negp = 0.f;
#pragma unroll
                for (int ct = 0; ct < 4; ++ct) {
                    const float dot = acc[rt][ct][reg];
                    const int j = jn[ct];
                    float cosv = dot * iinv * jinv[ct];
                    cosv = fminf(fmaxf(cosv, -1.f), 1.f);
                    float tn = fmaxf(fabsf(cosv) - M_NEG, 0.f);
                    const float nterm = tn * tn;
                    const float d2 = fmaxf(isq + jsq[ct] - 2.f * dot, 0.f);
                    float tp = fmaxf(sqrtf(d2) - M_POS, 0.f);
                    const float pterm = tp * tp;
                    const bool dg = (j == i);
                    if (rowValid) {
                        const bool in_r = (j >= ns) && (j <= ne);
                        if (in_r && !dg) posp += pterm;
                        if (!in_r || dg) negp += nterm;
                    }
                    if (!isDiag && jvalid[ct]) {
                        const bool in_c = (i >= jns[ct]) && (i <= jne[ct]);
                        if (in_c && !dg) posc[ct] += pterm;
                        if (!in_c || dg) negc[ct] += nterm;
                    }
                }
#pragma unroll
                for (int m = 1; m < 16; m <<= 1) {
                    posp += __shfl_xor(posp, m, 64);
                    negp += __shfl_xor(negp, m, 64);
                }
                if (rowValid && rl == 0) {
                    atomicAdd(&pos_acc[i], posp);
                    atomicAdd(&neg_acc[i], negp);
                }
            }
        }
        if (!isDiag) {
#pragma unroll
            for (int ct = 0; ct < 4; ++ct) {
                posc[ct] += __shfl_xor(posc[ct], 16, 64);
                posc[ct] += __shfl_xor(posc[ct], 32, 64);
                negc[ct] += __shfl_xor(negc[ct], 16, 64);
                negc[ct] += __shfl_xor(negc[ct], 32, 64);
            }
            if (q == 0) {
#pragma unroll
                for (int ct = 0; ct < 4; ++ct) {
                    if (jvalid[ct]) {
                        atomicAdd(&pos_acc[jn[ct]], posc[ct]);
                        atomicAdd(&neg_acc[jn[ct]], negc[ct]);
                    }
                }
            }
        }
    } else {
        // fast path: every element is a negative for both its row and its column
#pragma unroll
        for (int rt = 0; rt < 4; ++rt) {
            const int ibase = ilo + rt * 16 + q * 4;
#pragma unroll
            for (int reg = 0; reg < 4; ++reg) {
                const int i = ibase + reg;
                const float iinv = inv_norm[i];
                float negp = 0.f;
#pragma unroll
                for (int ct = 0; ct < 4; ++ct) {
                    const float dot = acc[rt][ct][reg];
                    float cosv = dot * iinv * jinv[ct];
                    cosv = fminf(fmaxf(cosv, -1.f), 1.f);
                    float tn = fmaxf(fabsf(cosv) - M_NEG, 0.f);
                    const float nterm = tn * tn;
                    negp += nterm;
                    negc[ct] += nterm;
                }
#pragma unroll
                for (int m = 1; m < 16; m <<= 1)
                    negp += __shfl_xor(negp, m, 64);
                if ((i < M) && rl == 0)
                    atomicAdd(&neg_acc[i], negp);
            }
        }
        if (!isDiag) {
#pragma unroll
            for (int ct = 0; ct < 4; ++ct) {
                negc[ct] += __shfl_xor(negc[ct], 16, 64);
                negc[ct] += __shfl_xor(negc[ct], 32, 64);
            }
            if (q == 0) {
#pragma unroll
                for (int ct = 0; ct < 4; ++ct)
                    if (jvalid[ct])
                        atomicAdd(&neg_acc[jn[ct]], negc[ct]);
            }
        }
    }

    // ---- last-block finalize (fence/atomic by lane0 only) ----
    __shared__ bool amLast;
    __syncthreads();
    if (lane == 0) {
        __threadfence();
        unsigned old = atomicAdd(counter, 1u);
        amLast = (old == (unsigned)(gridDim.x - 1));
    }
    __syncthreads();
    if (amLast) {
        __threadfence();
        float total = 0.f;
        int cnt = 0;
        for (int i = lane; i < M; i += 64) {
            const float pa = __hip_atomic_load(&pos_acc[i], __ATOMIC_RELAXED, __HIP_MEMORY_SCOPE_AGENT);
            const float na = __hip_atomic_load(&neg_acc[i], __ATOMIC_RELAXED, __HIP_MEMORY_SCOPE_AGENT);
            const int ns = starts[i], ne = ends[i];
            const int lo = max(ns, 0), hi = min(ne, N - 1);
            const int inr = max(hi - lo + 1, 0);
            const bool dg = (i >= ns) && (i <= ne);
            const int pos_cnt = inr - (dg ? 1 : 0);
            const int neg_cnt = N - inr + (dg ? 1 : 0);
            if (pos_cnt > 0 && neg_cnt > 0) {
                total += pa / (float)max(pos_cnt, 1)
                       + LAM_NEG * na / (float)max(neg_cnt, 1);
                cnt++;
            }
        }
        for (int o = 32; o > 0; o >>= 1) {
            total += __shfl_down(total, o, 64);
            cnt   += __shfl_down(cnt, o, 64);
        }
        if (lane == 0)
            out[0] = (cnt > 0) ? total / (float)cnt : 0.f;
    }
}

extern "C" void kernel_launch(void* const* d_in, const int* in_sizes, int n_in,
                              void* d_out, int out_size, void* d_ws, size_t ws_size,
                              hipStream_t stream) {
    const float* cb     = (const float*)d_in[0];
    const int*   starts = (const int*)d_in[1];
    const int*   ends   = (const int*)d_in[2];
    const int*   max_ip = (const int*)d_in[3];
    float* out = (float*)d_out;

    const int N = in_sizes[1];
    const int d = in_sizes[0] / N;

    char* ws = (char*)d_ws;
    unsigned char* cb_q = (unsigned char*)ws;
    size_t off = ((size_t)N * d + 255) & ~(size_t)255;
    float* sq       = (float*)(ws + off); off += (size_t)N * 4;
    float* inv_norm = (float*)(ws + off); off += (size_t)N * 4;
    float* pos_acc  = (float*)(ws + off); off += (size_t)N * 4;
    float* neg_acc  = (float*)(ws + off); off += (size_t)N * 4;
    unsigned* counter = (unsigned*)(ws + off); off += 256;

    // prep zeroes pos_acc/neg_acc/counter (2N+1 u32, contiguous)
    prep_kernel<<<N, 256, 0, stream>>>(cb, cb_q, sq, inv_norm,
                                       (unsigned*)pos_acc, 2 * N + 1, N, d);

    const int nb = N / 64;                    // 64-wide tiles, one wave each
    const int nBlocks = nb * (nb + 1) / 2;    // upper-triangular tiles
    gram_loss_kernel<<<nBlocks, 64, 0, stream>>>(cb_q, sq, inv_norm, starts, ends,
                                                 max_ip, pos_acc, neg_acc, counter,
                                                 out, N, d);
}

// Round 15
// 196.938 us; speedup vs baseline: 2.0743x; 2.0743x over previous
//
#include <hip/hip_runtime.h>
#include <hip/hip_bf16.h>
#include <stdint.h>

#define M_POS 0.5f
#define M_NEG 0.1f
#define LAM_NEG 1.0f

typedef __attribute__((ext_vector_type(4))) float floatx4;  // 16x16 MFMA accumulator
typedef __attribute__((ext_vector_type(8))) int   intx8;    // 32B fp8 operand (K=128)

union Frag8 { intx8 v; int4 q[2]; };

// ---------------- Kernel A: row sumsq, inv_norm, fp32 -> fp8(e4m3) quantize, zero accs ----
__global__ __launch_bounds__(256) void prep_kernel(
    const float* __restrict__ cb, unsigned char* __restrict__ cb_q,
    float* __restrict__ sq, float* __restrict__ inv_norm,
    unsigned* __restrict__ zero_base, int zero_len,
    int N, int d)
{
    const int gi = blockIdx.x * 256 + threadIdx.x;
    if (gi < zero_len) zero_base[gi] = 0u;

    const int row = blockIdx.x;
    const float* src = cb + (size_t)row * d;
    unsigned char* dst = cb_q + (size_t)row * d;
    const int t = threadIdx.x;

    float s = 0.f;
    for (int c = t * 4; c < d; c += 1024) {
        float4 v = *(const float4*)(src + c);
        s += v.x * v.x + v.y * v.y + v.z * v.z + v.w * v.w;
        int pk = __builtin_amdgcn_cvt_pk_fp8_f32(v.x, v.y, 0, false);   // bytes 0,1
        pk     = __builtin_amdgcn_cvt_pk_fp8_f32(v.z, v.w, pk, true);   // bytes 2,3
        *(int*)(dst + c) = pk;
    }
    for (int o = 32; o > 0; o >>= 1) s += __shfl_down(s, o, 64);
    __shared__ float wsum[4];
    if ((t & 63) == 0) wsum[t >> 6] = s;
    __syncthreads();
    if (t == 0) {
        float tot = wsum[0] + wsum[1] + wsum[2] + wsum[3];
        sq[row] = tot;
        inv_norm[row] = rsqrtf(tot);
    }
}

// ---------------- Kernel B: fused symmetric MX-fp8 Gram GEMM + loss epilogue + finalize ----
// R15 = R8's kernel (BEST gram: 128.5 us — 16x16x128 MX-fp8 unit-scale, single-buffer
// BK=128, 128x128 triangular tiles, (256,3)) + XCD-AWARE TILE SWIZZLE:
// blockIdx -> XCD is round-robin (% 8), so vt = (blockIdx%8)*(nBlocks/8) + blockIdx/8
// hands each XCD a CONTIGUOUS triangular range (contiguous bx strips). A strip's
// working set (~4 MB fp8 rows) then fits that XCD's 4 MB L2 -> fewer L2 misses ->
// lower staging-service latency. FETCH_SIZE is the canary (expect big drop).
// Established DO-NOTs: 64KB dbuf (R9), per-thread fences (R3), (256,4)+MX (R10 spills),
// 32x32x64 MX (R6), 1-wave blocks (R14), 32KB dbuf (R11 — slower than single).
__global__ __launch_bounds__(256, 3) void gram_loss_kernel(
    const unsigned char* __restrict__ A,   // N x d fp8
    const float* __restrict__ sq, const float* __restrict__ inv_norm,
    const int* __restrict__ starts, const int* __restrict__ ends,
    const int* __restrict__ max_ip,
    float* __restrict__ pos_acc, float* __restrict__ neg_acc,
    unsigned* __restrict__ counter, float* __restrict__ out,
    int N, int d)
{
    const int M = min(N, max_ip[0] + 1);

    // XCD-aware remap: contiguous tile ranges per XCD (gridDim.x divisible by 8 when
    // nb is even; fall back to identity otherwise).
    int vt = blockIdx.x;
    const int nB = gridDim.x;
    if ((nB & 7) == 0) {
        const int per = nB >> 3;
        vt = (blockIdx.x & 7) * per + (blockIdx.x >> 3);
    }

    // triangular decode: vt -> (by, bx), by <= bx
    int bx = (int)((sqrtf(8.f * (float)vt + 1.f) - 1.f) * 0.5f);
    while ((bx + 1) * (bx + 2) / 2 <= vt) bx++;
    while (bx * (bx + 1) / 2 > vt) bx--;
    const int by = vt - bx * (bx + 1) / 2;

    const int rowBase = by * 128;
    const int colBase = bx * 128;
    const bool isDiag = (by == bx);

    __shared__ alignas(16) unsigned char ldsA[128 * 128];
    __shared__ alignas(16) unsigned char ldsB[128 * 128];

    const int tid  = threadIdx.x;
    const int wave = tid >> 6;
    const int lane = tid & 63;
    const int wr = (wave >> 1) * 64;
    const int wc = (wave & 1) * 64;

    floatx4 acc[4][4];
#pragma unroll
    for (int a = 0; a < 4; ++a)
#pragma unroll
        for (int b = 0; b < 4; ++b) acc[a][b] = (floatx4){0.f, 0.f, 0.f, 0.f};

    // staging: per issue, 8 rows x 8 chunks; dst lane-linear; src chunk xor lane-constant.
    const int sRow = lane >> 3;                         // 0..7
    const int sChk = lane & 7;                          // 16B chunk 0..7
    const int srcOffC = ((sChk ^ sRow) * 16);
    const int kTiles = d / 128;                         // 8

    // fragment-read constants: lane holds k = (lane>>4)*32 .. +31 of its row
    const int rl = lane & 15;
    const int g  = lane >> 4;       // 0..3 (k-group)
    const int rx = rl & 7;
    const int c0 = (((2 * g)     ^ rx) * 16);
    const int c1 = (((2 * g + 1) ^ rx) * 16);

    for (int kt = 0; kt < kTiles; ++kt) {
        __syncthreads();
        const int k0 = kt * 128;
#pragma unroll
        for (int h = 0; h < 4; ++h) {
            const int r = wave * 32 + h * 8 + sRow;     // tile row 0..127
            const unsigned char* ga = A + (size_t)(rowBase + r) * d + k0 + srcOffC;
            const unsigned char* gb = A + (size_t)(colBase + r) * d + k0 + srcOffC;
            __builtin_amdgcn_global_load_lds(
                (const __attribute__((address_space(1))) void*)ga,
                (__attribute__((address_space(3))) void*)(ldsA + r * 128 + sChk * 16), 16, 0, 0);
            __builtin_amdgcn_global_load_lds(
                (const __attribute__((address_space(1))) void*)gb,
                (__attribute__((address_space(3))) void*)(ldsB + r * 128 + sChk * 16), 16, 0, 0);
        }
        __syncthreads();

        Frag8 af[4], bf[4];
#pragma unroll
        for (int t4 = 0; t4 < 4; ++t4) {
            const unsigned char* pa = ldsA + (wr + t4 * 16 + rl) * 128;
            af[t4].q[0] = *(const int4*)(pa + c0);
            af[t4].q[1] = *(const int4*)(pa + c1);
            const unsigned char* pb = ldsB + (wc + t4 * 16 + rl) * 128;
            bf[t4].q[0] = *(const int4*)(pb + c0);
            bf[t4].q[1] = *(const int4*)(pb + c1);
        }
#pragma unroll
        for (int rt = 0; rt < 4; ++rt)
#pragma unroll
            for (int ct = 0; ct < 4; ++ct)
                acc[rt][ct] = __builtin_amdgcn_mfma_scale_f32_16x16x128_f8f6f4(
                    af[rt].v, bf[ct].v, acc[rt][ct], 0, 0, 0, 127, 0, 127);
    }

    // ---- epilogue (16x16 C/D: col=lane&15, row=(lane>>4)*4+reg) ----
    const int q  = lane >> 4;
    const int jlo = colBase + wc;
    const int ilo = rowBase + wr;

    int   jn[4];
    float jinv[4];
    bool  jvalid[4];
#pragma unroll
    for (int ct = 0; ct < 4; ++ct) {
        const int j = jlo + ct * 16 + rl;
        jn[ct]  = j;
        jinv[ct] = inv_norm[j];
        jvalid[ct] = (j < M);
    }

    // wave-uniform positive-pair possibility check
    bool posLane = false;
    {
        const int ri = ilo + lane;
        if (ri < M) posLane |= (ends[ri] >= jlo) && (starts[ri] <= jlo + 63);
        if (!isDiag) {
            const int cj = jlo + lane;
            if (cj < M) posLane |= (ends[cj] >= ilo) && (starts[cj] <= ilo + 63);
        }
    }
    const bool fullPath = (__ballot(posLane) != 0ULL);

    float posc[4] = {0.f, 0.f, 0.f, 0.f};
    float negc[4] = {0.f, 0.f, 0.f, 0.f};

    if (fullPath) {
        int   jns[4], jne[4];
        float jsq[4];
#pragma unroll
        for (int ct = 0; ct < 4; ++ct) {
            jsq[ct] = sq[jn[ct]];
            jns[ct] = jvalid[ct] ? starts[jn[ct]] : 0;
            jne[ct] = jvalid[ct] ? ends[jn[ct]]   : -1;
        }
#pragma unroll
        for (int rt = 0; rt < 4; ++rt) {
            const int ibase = ilo + rt * 16 + q * 4;
#pragma unroll
            for (int reg = 0; reg < 4; ++reg) {
                const int i = ibase + reg;
                const bool rowValid = (i < M);
                const int ns = rowValid ? starts[i] : 0;
                const int ne = rowValid ? ends[i]   : -1;
                const float iinv = inv_norm[i];
                const float isq  = sq[i];
                float posp = 0.f, negp = 0.f;
#pragma unroll
                for (int ct = 0; ct < 4; ++ct) {
                    const float dot = acc[rt][ct][reg];
                    const int j = jn[ct];
                    float cosv = dot * iinv * jinv[ct];
                    cosv = fminf(fmaxf(cosv, -1.f), 1.f);
                    float tn = fmaxf(fabsf(cosv) - M_NEG, 0.f);
                    const float nterm = tn * tn;
                    const float d2 = fmaxf(isq + jsq[ct] - 2.f * dot, 0.f);
                    float tp = fmaxf(sqrtf(d2) - M_POS, 0.f);
                    const float pterm = tp * tp;
                    const bool dg = (j == i);
                    if (rowValid) {
                        const bool in_r = (j >= ns) && (j <= ne);
                        if (in_r && !dg) posp += pterm;
                        if (!in_r || dg) negp += nterm;
                    }
                    if (!isDiag && jvalid[ct]) {
                        const bool in_c = (i >= jns[ct]) && (i <= jne[ct]);
                        if (in_c && !dg) posc[ct] += pterm;
                        if (!in_c || dg) negc[ct] += nterm;
                    }
                }
#pragma unroll
                for (int m = 1; m < 16; m <<= 1) {
                    posp += __shfl_xor(posp, m, 64);
                    negp += __shfl_xor(negp, m, 64);
                }
                if (rowValid && rl == 0) {
                    atomicAdd(&pos_acc[i], posp);
                    atomicAdd(&neg_acc[i], negp);
                }
            }
        }
        if (!isDiag) {
#pragma unroll
            for (int ct = 0; ct < 4; ++ct) {
                posc[ct] += __shfl_xor(posc[ct], 16, 64);
                posc[ct] += __shfl_xor(posc[ct], 32, 64);
                negc[ct] += __shfl_xor(negc[ct], 16, 64);
                negc[ct] += __shfl_xor(negc[ct], 32, 64);
            }
            if (q == 0) {
#pragma unroll
                for (int ct = 0; ct < 4; ++ct) {
                    if (jvalid[ct]) {
                        atomicAdd(&pos_acc[jn[ct]], posc[ct]);
                        atomicAdd(&neg_acc[jn[ct]], negc[ct]);
                    }
                }
            }
        }
    } else {
        // fast path: every element is a negative for both its row and its column
#pragma unroll
        for (int rt = 0; rt < 4; ++rt) {
            const int ibase = ilo + rt * 16 + q * 4;
#pragma unroll
            for (int reg = 0; reg < 4; ++reg) {
                const int i = ibase + reg;
                const float iinv = inv_norm[i];
                float negp = 0.f;
#pragma unroll
                for (int ct = 0; ct < 4; ++ct) {
                    const float dot = acc[rt][ct][reg];
                    float cosv = dot * iinv * jinv[ct];
                    cosv = fminf(fmaxf(cosv, -1.f), 1.f);
                    float tn = fmaxf(fabsf(cosv) - M_NEG, 0.f);
                    const float nterm = tn * tn;
                    negp += nterm;
                    negc[ct] += nterm;
                }
#pragma unroll
                for (int m = 1; m < 16; m <<= 1)
                    negp += __shfl_xor(negp, m, 64);
                if ((i < M) && rl == 0)
                    atomicAdd(&neg_acc[i], negp);
            }
        }
        if (!isDiag) {
#pragma unroll
            for (int ct = 0; ct < 4; ++ct) {
                negc[ct] += __shfl_xor(negc[ct], 16, 64);
                negc[ct] += __shfl_xor(negc[ct], 32, 64);
            }
            if (q == 0) {
#pragma unroll
                for (int ct = 0; ct < 4; ++ct)
                    if (jvalid[ct])
                        atomicAdd(&neg_acc[jn[ct]], negc[ct]);
            }
        }
    }

    // ---- last-block finalize (fence/atomic by tid0 only — validated R7) ----
    __shared__ bool amLast;
    __syncthreads();
    if (tid == 0) {
        __threadfence();
        unsigned old = atomicAdd(counter, 1u);
        amLast = (old == (unsigned)(gridDim.x - 1));
    }
    __syncthreads();
    if (amLast) {
        __threadfence();
        float total = 0.f;
        int cnt = 0;
        for (int i = tid; i < M; i += 256) {
            const float pa = __hip_atomic_load(&pos_acc[i], __ATOMIC_RELAXED, __HIP_MEMORY_SCOPE_AGENT);
            const float na = __hip_atomic_load(&neg_acc[i], __ATOMIC_RELAXED, __HIP_MEMORY_SCOPE_AGENT);
            const int ns = starts[i], ne = ends[i];
            const int lo = max(ns, 0), hi = min(ne, N - 1);
            const int inr = max(hi - lo + 1, 0);
            const bool dg = (i >= ns) && (i <= ne);
            const int pos_cnt = inr - (dg ? 1 : 0);
            const int neg_cnt = N - inr + (dg ? 1 : 0);
            if (pos_cnt > 0 && neg_cnt > 0) {
                total += pa / (float)max(pos_cnt, 1)
                       + LAM_NEG * na / (float)max(neg_cnt, 1);
                cnt++;
            }
        }
        for (int o = 32; o > 0; o >>= 1) {
            total += __shfl_down(total, o, 64);
            cnt   += __shfl_down(cnt, o, 64);
        }
        __shared__ float fin_ts[4];
        __shared__ int   fin_cs[4];
        if ((tid & 63) == 0) { fin_ts[tid >> 6] = total; fin_cs[tid >> 6] = cnt; }
        __syncthreads();
        if (tid == 0) {
            float T = fin_ts[0] + fin_ts[1] + fin_ts[2] + fin_ts[3];
            int   C = fin_cs[0] + fin_cs[1] + fin_cs[2] + fin_cs[3];
            out[0] = (C > 0) ? T / (float)C : 0.f;
        }
    }
}

extern "C" void kernel_launch(void* const* d_in, const int* in_sizes, int n_in,
                              void* d_out, int out_size, void* d_ws, size_t ws_size,
                              hipStream_t stream) {
    const float* cb     = (const float*)d_in[0];
    const int*   starts = (const int*)d_in[1];
    const int*   ends   = (const int*)d_in[2];
    const int*   max_ip = (const int*)d_in[3];
    float* out = (float*)d_out;

    const int N = in_sizes[1];
    const int d = in_sizes[0] / N;

    char* ws = (char*)d_ws;
    unsigned char* cb_q = (unsigned char*)ws;
    size_t off = ((size_t)N * d + 255) & ~(size_t)255;
    float* sq       = (float*)(ws + off); off += (size_t)N * 4;
    float* inv_norm = (float*)(ws + off); off += (size_t)N * 4;
    float* pos_acc  = (float*)(ws + off); off += (size_t)N * 4;
    float* neg_acc  = (float*)(ws + off); off += (size_t)N * 4;
    unsigned* counter = (unsigned*)(ws + off); off += 256;

    // prep zeroes pos_acc/neg_acc/counter (2N+1 u32, contiguous)
    prep_kernel<<<N, 256, 0, stream>>>(cb, cb_q, sq, inv_norm,
                                       (unsigned*)pos_acc, 2 * N + 1, N, d);

    const int nb = N / 128;
    const int nBlocks = nb * (nb + 1) / 2;   // upper-triangular tiles
    gram_loss_kernel<<<nBlocks, 256, 0, stream>>>(cb_q, sq, inv_norm, starts, ends,
                                                  max_ip, pos_acc, neg_acc, counter,
                                                  out, N, d);
}